// Round 2
// baseline (287.345 us; speedup 1.0000x reference)
//
#include <hip/hip_runtime.h>

// ModulatedConv2d (StyleGAN2): B=8, Cin=Cout=512, k=3, H=W=64.
//   s[b,c]     = style @ (mod_weight/sqrt(512))^T + bias          (fp32)
//   scale[b,o] = cs * rsqrt(cs^2 * sum_c wsq[o,c]*s^2 + eps)
//   out[b,o,p] = scale[b,o] * sum_{c,k} w[o,c,k] * (s[b,c]*x[b,c,p'])
// k_conv v2: K-chunked LDS layout (each 16B entry = one MFMA fragment slice)
// -> every ds_read_b128 is 512B contiguous per half-wave = conflict-free.
// Wave tile 64o x 128px (2 y-rows): 6 reads / 8 MFMA per tap (was 4/4).

typedef __bf16 bf16x8 __attribute__((ext_vector_type(8)));
typedef float f32x16 __attribute__((ext_vector_type(16)));

__device__ __forceinline__ unsigned short f2bf(float f) {
  union { float f; unsigned int u; } v; v.f = f;
  unsigned int u = v.u;
  return (unsigned short)((u + 0x7fffu + ((u >> 16) & 1u)) >> 16);
}

// s[b,c] = sum_d style[b,d]*mw[c,d]*(1/sqrt(512)) + mb[c]; also zero the zeropage
__global__ void k_mod(const float* __restrict__ style, const float* __restrict__ mw,
                      const float* __restrict__ mb, float* __restrict__ s,
                      float* __restrict__ zp) {
  int t = blockIdx.x * 256 + threadIdx.x;   // 4096
  if (blockIdx.x == 0) zp[threadIdx.x] = 0.f;  // 1KB zero page
  int b = t >> 9, c = t & 511;
  float acc = 0.f;
  for (int d = 0; d < 512; ++d) acc += style[b * 512 + d] * mw[c * 512 + d];
  s[t] = acc * 0.04419417382415922f + mb[c];  // 1/sqrt(512)
}

// wsq[o,c] = sum_k w^2 ; wbf[k][o][c] = bf16(w[o][c][k])
__global__ void k_wprep(const float* __restrict__ w, float* __restrict__ wsq,
                        unsigned short* __restrict__ wbf) {
  int t = blockIdx.x * 256 + threadIdx.x;   // 262144
  int o = t >> 9, c = t & 511;
  const float* wp = w + (size_t)(o * 512 + c) * 9;
  float q = 0.f;
#pragma unroll
  for (int k = 0; k < 9; ++k) {
    float v = wp[k];
    q += v * v;
    wbf[((size_t)k * 512 + o) * 512 + c] = f2bf(v);
  }
  wsq[t] = q;
}

// scale[b,o] = cs * rsqrt(cs^2 * sum_c wsq[o,c]*s[b,c]^2 + 1e-8)
__global__ void k_scale(const float* __restrict__ wsq, const float* __restrict__ s,
                        float* __restrict__ scale) {
  int t = blockIdx.x * 256 + threadIdx.x;   // 4096
  int b = t >> 9, o = t & 511;
  float acc = 0.f;
  for (int c = 0; c < 512; ++c) {
    float sv = s[b * 512 + c];
    acc += wsq[o * 512 + c] * sv * sv;
  }
  const float cs = 0.014731391274719739f;   // 1/sqrt(4608)
  scale[t] = cs * rsqrtf(cs * cs * acc + 1e-8f);
}

// xt[b][y][x][c] = bf16(s[b,c] * x[b,c,y,x])   (channel-contiguous for MFMA K)
__global__ void k_xt(const float* __restrict__ x, const float* __restrict__ s,
                     unsigned short* __restrict__ xt) {
  int bid = blockIdx.x;                     // 8*16*64 = 8192
  int b = bid >> 10, cc = (bid >> 6) & 15, y = bid & 63;
  int t = threadIdx.x;
  int ci = t >> 3, xg = t & 7;
  int c = cc * 32 + ci;
  const float* xp = x + (((size_t)(b * 512 + c) * 64 + y) * 64 + xg * 8);
  float sv = s[b * 512 + c];
  float4 v0 = *(const float4*)xp;
  float4 v1 = *(const float4*)(xp + 4);
  unsigned short r[8];
  r[0] = f2bf(v0.x * sv); r[1] = f2bf(v0.y * sv);
  r[2] = f2bf(v0.z * sv); r[3] = f2bf(v0.w * sv);
  r[4] = f2bf(v1.x * sv); r[5] = f2bf(v1.y * sv);
  r[6] = f2bf(v1.z * sv); r[7] = f2bf(v1.w * sv);
  size_t base = ((size_t)(b * 64 + y) * 64) * 512 + c;
#pragma unroll
  for (int j = 0; j < 8; ++j) xt[base + (size_t)(xg * 8 + j) * 512] = r[j];
}

// ---------------- k_conv v2 ----------------
// LDS map (bytes), single buffer, 40 issues x 1024B = 40960 B:
//   X region: issues 0..20  : entries e=0..1343, entry = 16B = 8 c-values
//             e -> chunk(=hi) = e/660, r = (e%660)/66, xi = e%66
//             holds xt[y0+r-1][xi-1][cc*16 + chunk*8 + 0..7]   (zp if OOB)
//   W region: issues 21..38 : e2 -> chunk = e2/576, tap = (e2%576)/64, o = e2%64
//             holds wbf[tap][ob*64+o][cc*16 + chunk*8 + 0..7]
//   issue 39: dummy (pad)
// Fragment read = 32 consecutive 16B entries per half-wave -> conflict-free.
#define WOFF_US 10752   // 21*512 (ushort index of W region)

__global__ __launch_bounds__(256, 2) void k_conv(
    const unsigned short* __restrict__ xt, const unsigned short* __restrict__ wbf,
    const float* __restrict__ scale, const float* __restrict__ zp,
    float* __restrict__ out) {
  __shared__ __align__(16) unsigned short lds[20480];  // 40960 B

  int bid = blockIdx.x;                    // 512 = 8 ob * 8 b * 8 yg
  // XCD-aware swizzle: blocks on one XCD share ob (W panel L2-resident)
  int vid = ((bid & 7) << 6) + (bid >> 3);
  int ob = vid >> 6;
  int b  = (vid >> 3) & 7;
  int yg = vid & 7;
  int y0 = yg << 3;

  int tid = threadIdx.x;
  int wy = tid >> 6, lane = tid & 63;
  int ln31 = lane & 31, hi = lane >> 5;

  // ---- precompute staging source pointers (10 issues per thread) ----
  const char* srcp[10];
  const char* xglob = (const char*)(xt + (size_t)b * 64 * 64 * 512);
#pragma unroll
  for (int i = 0; i < 10; ++i) {
    int is = wy + i * 4;
    const char* p;
    if (is < 21) {
      int e = is * 64 + lane;
      int chunk = e / 660;
      int rem = e % 660;
      int r = rem / 66;
      int xi = rem % 66;
      int y = y0 + r - 1;
      int x = xi - 1;
      bool ok = (e < 1320) && (y >= 0) && (y < 64) && (x >= 0) && (x < 64);
      p = ok ? xglob + 2 * ((y * 64 + x) * 512 + chunk * 8) : (const char*)zp;
    } else if (is < 39) {
      int e2 = (is - 21) * 64 + lane;
      int chunk = e2 / 576;
      int rem = e2 % 576;
      int tap = rem >> 6;
      int o = rem & 63;
      p = (const char*)wbf + 2 * (((tap * 512 + ob * 64 + o) * 512) + chunk * 8);
    } else {
      p = (const char*)zp;
    }
    srcp[i] = p;
  }

  f32x16 zero = {0,0,0,0,0,0,0,0,0,0,0,0,0,0,0,0};
  f32x16 acc[8];   // [oh*4 + rs*2 + xb], all indices compile-time
#pragma unroll
  for (int i = 0; i < 8; ++i) acc[i] = zero;

  // compute-phase LDS bases (bf16-element units; reads use base + const imm)
  const unsigned short* Xb = &lds[(hi * 660 + (wy << 1) * 66 + ln31) * 8];
  const unsigned short* Ab = &lds[WOFF_US + (hi * 576 + ln31) * 8];

  for (int cc = 0; cc < 32; ++cc) {
    __syncthreads();
#pragma unroll
    for (int i = 0; i < 10; ++i) {
      __builtin_amdgcn_global_load_lds(
          (const __attribute__((address_space(1))) void*)(srcp[i] + cc * 32),
          (__attribute__((address_space(3))) void*)&lds[(wy + i * 4) * 512],
          16, 0, 0);
    }
    __syncthreads();
#pragma unroll
    for (int tap = 0; tap < 9; ++tap) {
      const int ky = tap / 3, kx = tap % 3;
      bf16x8 a0 = *(const bf16x8*)&Ab[(tap * 64) * 8];
      bf16x8 a1 = *(const bf16x8*)&Ab[(tap * 64 + 32) * 8];
#pragma unroll
      for (int rs = 0; rs < 2; ++rs) {
#pragma unroll
        for (int xb = 0; xb < 2; ++xb) {
          bf16x8 bv = *(const bf16x8*)&Xb[((rs + ky) * 66 + xb * 32 + kx) * 8];
          acc[0 + rs * 2 + xb] =
              __builtin_amdgcn_mfma_f32_32x32x16_bf16(a0, bv, acc[0 + rs * 2 + xb], 0, 0, 0);
          acc[4 + rs * 2 + xb] =
              __builtin_amdgcn_mfma_f32_32x32x16_bf16(a1, bv, acc[4 + rs * 2 + xb], 0, 0, 0);
        }
      }
    }
  }

  // ---- epilogue: C/D layout col=lane&31, row=(reg&3)+8*(reg>>2)+4*(lane>>5) ----
  int yout = y0 + (wy << 1);
  const float* scp = scale + b * 512 + ob * 64;
  float* op = out + ((size_t)(b * 512 + ob * 64) * 64) * 64;
#pragma unroll
  for (int oh = 0; oh < 2; ++oh) {
#pragma unroll
    for (int rs = 0; rs < 2; ++rs) {
#pragma unroll
      for (int xb = 0; xb < 2; ++xb) {
        const f32x16& A = acc[oh * 4 + rs * 2 + xb];
#pragma unroll
        for (int reg = 0; reg < 16; ++reg) {
          int row = (reg & 3) + 8 * (reg >> 2) + hi * 4;
          int o = oh * 32 + row;
          float sc = scp[o];
          op[((size_t)o * 64 + (yout + rs)) * 64 + xb * 32 + ln31] = A[reg] * sc;
        }
      }
    }
  }
}

extern "C" void kernel_launch(void* const* d_in, const int* in_sizes, int n_in,
                              void* d_out, int out_size, void* d_ws, size_t ws_size,
                              hipStream_t stream) {
  const float* x     = (const float*)d_in[0];  // [8,512,64,64]
  const float* style = (const float*)d_in[1];  // [8,512]
  const float* w     = (const float*)d_in[2];  // [1,512,512,3,3]
  const float* mw    = (const float*)d_in[3];  // [512,512]
  const float* mb    = (const float*)d_in[4];  // [512]
  float* out = (float*)d_out;

  char* ws = (char*)d_ws;
  float* zp    = (float*)ws;                       // 1 KB zeros
  float* s     = (float*)(ws + 1024);              // 16 KB
  float* scale = (float*)(ws + 17408);             // 16 KB
  float* wsq   = (float*)(ws + 33792);             // 1 MB
  unsigned short* wbf = (unsigned short*)(ws + 1082368);   // 4.72 MB  [9][512][512]
  unsigned short* xt  = (unsigned short*)(ws + 5800960);   // 33.5 MB  [8][64][64][512]

  k_mod  <<<16,   256, 0, stream>>>(style, mw, mb, s, zp);
  k_wprep<<<1024, 256, 0, stream>>>(w, wsq, wbf);
  k_scale<<<16,   256, 0, stream>>>(wsq, s, scale);
  k_xt   <<<8192, 256, 0, stream>>>(x, s, xt);
  k_conv <<<512,  256, 0, stream>>>(xt, wbf, scale, zp, out);
}

// Round 3
// 248.915 us; speedup vs baseline: 1.1544x; 1.1544x over previous
//
#include <hip/hip_runtime.h>

// ModulatedConv2d (StyleGAN2): B=8, Cin=Cout=512, k=3, H=W=64.
//   s[b,c]     = style @ (mod_weight/sqrt(512))^T + bias          (fp32)
//   scale[b,o] = cs * rsqrt(cs^2 * sum_c wsq[o,c]*s^2 + eps)
//   out[b,o,p] = scale[b,o] * sum_{c,k} w[o,c,k] * (s[b,c]*x[b,c,p'])
// k_conv v3: double-buffered LDS (2x40KB) + counted vmcnt(10) pipeline
// (raw s_barrier + inline-asm waitcnt), setprio around MFMA, kx-hoisted
// X fragments (42 ds_read/phase vs 54), XCD swizzle shares b (the 33.5MB
// tensor) per XCD instead of the 4.7MB W.

typedef __bf16 bf16x8 __attribute__((ext_vector_type(8)));
typedef float f32x16 __attribute__((ext_vector_type(16)));

#define AS1 __attribute__((address_space(1)))
#define AS3 __attribute__((address_space(3)))

__device__ __forceinline__ unsigned short f2bf(float f) {
  union { float f; unsigned int u; } v; v.f = f;
  unsigned int u = v.u;
  return (unsigned short)((u + 0x7fffu + ((u >> 16) & 1u)) >> 16);
}

__global__ void k_mod(const float* __restrict__ style, const float* __restrict__ mw,
                      const float* __restrict__ mb, float* __restrict__ s,
                      float* __restrict__ zp) {
  int t = blockIdx.x * 256 + threadIdx.x;   // 4096
  if (blockIdx.x == 0) zp[threadIdx.x] = 0.f;  // 1KB zero page
  int b = t >> 9, c = t & 511;
  float acc = 0.f;
  for (int d = 0; d < 512; ++d) acc += style[b * 512 + d] * mw[c * 512 + d];
  s[t] = acc * 0.04419417382415922f + mb[c];  // 1/sqrt(512)
}

__global__ void k_wprep(const float* __restrict__ w, float* __restrict__ wsq,
                        unsigned short* __restrict__ wbf) {
  int t = blockIdx.x * 256 + threadIdx.x;   // 262144
  int o = t >> 9, c = t & 511;
  const float* wp = w + (size_t)(o * 512 + c) * 9;
  float q = 0.f;
#pragma unroll
  for (int k = 0; k < 9; ++k) {
    float v = wp[k];
    q += v * v;
    wbf[((size_t)k * 512 + o) * 512 + c] = f2bf(v);
  }
  wsq[t] = q;
}

__global__ void k_scale(const float* __restrict__ wsq, const float* __restrict__ s,
                        float* __restrict__ scale) {
  int t = blockIdx.x * 256 + threadIdx.x;   // 4096
  int b = t >> 9, o = t & 511;
  float acc = 0.f;
  for (int c = 0; c < 512; ++c) {
    float sv = s[b * 512 + c];
    acc += wsq[o * 512 + c] * sv * sv;
  }
  const float cs = 0.014731391274719739f;   // 1/sqrt(4608)
  scale[t] = cs * rsqrtf(cs * cs * acc + 1e-8f);
}

// xt[b][y][x][c] = bf16(s[b,c] * x[b,c,y,x])
__global__ void k_xt(const float* __restrict__ x, const float* __restrict__ s,
                     unsigned short* __restrict__ xt) {
  int bid = blockIdx.x;                     // 8*16*64 = 8192
  int b = bid >> 10, cc = (bid >> 6) & 15, y = bid & 63;
  int t = threadIdx.x;
  int ci = t >> 3, xg = t & 7;
  int c = cc * 32 + ci;
  const float* xp = x + (((size_t)(b * 512 + c) * 64 + y) * 64 + xg * 8);
  float sv = s[b * 512 + c];
  float4 v0 = *(const float4*)xp;
  float4 v1 = *(const float4*)(xp + 4);
  unsigned short r[8];
  r[0] = f2bf(v0.x * sv); r[1] = f2bf(v0.y * sv);
  r[2] = f2bf(v0.z * sv); r[3] = f2bf(v0.w * sv);
  r[4] = f2bf(v1.x * sv); r[5] = f2bf(v1.y * sv);
  r[6] = f2bf(v1.z * sv); r[7] = f2bf(v1.w * sv);
  size_t base = ((size_t)(b * 64 + y) * 64) * 512 + c;
#pragma unroll
  for (int j = 0; j < 8; ++j) xt[base + (size_t)(xg * 8 + j) * 512] = r[j];
}

// ---------------- k_conv v3 ----------------
// Per 40KB buffer (40 issues x 1024B):
//   X: issues 0..20 : entry e = chunk(0..1)*660 + r(0..9)*66 + xi(0..65)
//      holds xt[y0+r-1][xi-1][cc*16 + chunk*8 + 0..7]   (zp if OOB/pad)
//   W: issues 21..38: e2 = chunk*576 + tap*64 + o
//      holds wbf[tap][ob*64+o][cc*16 + chunk*8 + 0..7]
//   issue 39: dummy (zp)
#define WOFF_US 10752   // 21*512
#define BUFU    20480   // ushorts per buffer (40KB)

__global__ __launch_bounds__(256, 2) void k_conv(
    const unsigned short* __restrict__ xt, const unsigned short* __restrict__ wbf,
    const float* __restrict__ scale, const float* __restrict__ zp,
    float* __restrict__ out) {
  __shared__ __align__(16) unsigned short lds[2 * BUFU];  // 81920 B

  int bid = blockIdx.x;            // 512 = 8 b * 8 yg * 8 ob
  int b   = bid & 7;               // round-robin => XCD k owns batch b=k
  int rest = bid >> 3;
  int yg  = rest & 7;
  int ob  = rest >> 3;
  int y0  = yg << 3;

  int tid = threadIdx.x;
  int wy = tid >> 6, lane = tid & 63;
  int ln31 = lane & 31, hi = lane >> 5;

  // ---- staging source pointers (10 issues per thread), advance 32B/phase ----
  const char* srcp[10];
  const char* xglob = (const char*)(xt + (size_t)b * 64 * 64 * 512);
#pragma unroll
  for (int i = 0; i < 10; ++i) {
    int is = wy + i * 4;
    const char* p;
    if (is < 21) {
      int e = is * 64 + lane;
      int chunk = e / 660;
      int rem = e % 660;
      int r = rem / 66, xi = rem % 66;
      int y = y0 + r - 1, x = xi - 1;
      bool ok = (e < 1320) && (y >= 0) && (y < 64) && (x >= 0) && (x < 64);
      p = ok ? xglob + 2 * ((y * 64 + x) * 512 + chunk * 8) : (const char*)zp;
    } else if (is < 39) {
      int e2 = (is - 21) * 64 + lane;
      int chunk = e2 / 576;
      int rem = e2 % 576;
      int tap = rem >> 6, o = rem & 63;
      p = (const char*)wbf + 2 * ((tap * 512 + ob * 64 + o) * 512 + chunk * 8);
    } else {
      p = (const char*)zp;
    }
    srcp[i] = p;
  }

  f32x16 acc[8];   // [oh*4 + rs*2 + xb]
#pragma unroll
  for (int i = 0; i < 8; ++i)
    acc[i] = (f32x16){0,0,0,0,0,0,0,0,0,0,0,0,0,0,0,0};

  auto STAGE = [&](int bufu) {
#pragma unroll
    for (int i = 0; i < 10; ++i) {
      __builtin_amdgcn_global_load_lds(
          (const AS1 void*)srcp[i],
          (AS3 void*)&lds[bufu + (wy + i * 4) * 512], 16, 0, 0);
      srcp[i] += 32;
    }
  };

  auto COMPUTE = [&](const unsigned short* Xbp, const unsigned short* Abp) {
#pragma unroll
    for (int kx = 0; kx < 3; ++kx) {
      bf16x8 bv[8];  // rows (wy*2 + 0..3) x xb(0..1) at this kx
#pragma unroll
      for (int rr = 0; rr < 4; ++rr)
#pragma unroll
        for (int xb = 0; xb < 2; ++xb)
          bv[rr * 2 + xb] = *(const bf16x8*)&Xbp[(rr * 66 + xb * 32 + kx) * 8];
#pragma unroll
      for (int ky = 0; ky < 3; ++ky) {
        const int tap = ky * 3 + kx;
        bf16x8 a0 = *(const bf16x8*)&Abp[tap * 512];
        bf16x8 a1 = *(const bf16x8*)&Abp[tap * 512 + 256];
#pragma unroll
        for (int rs = 0; rs < 2; ++rs)
#pragma unroll
          for (int xb = 0; xb < 2; ++xb) {
            acc[rs * 2 + xb] = __builtin_amdgcn_mfma_f32_32x32x16_bf16(
                a0, bv[(rs + ky) * 2 + xb], acc[rs * 2 + xb], 0, 0, 0);
            acc[4 + rs * 2 + xb] = __builtin_amdgcn_mfma_f32_32x32x16_bf16(
                a1, bv[(rs + ky) * 2 + xb], acc[4 + rs * 2 + xb], 0, 0, 0);
          }
      }
    }
  };

  const unsigned short* Xb0 = &lds[(hi * 660 + (wy << 1) * 66 + ln31) * 8];
  const unsigned short* Ab0 = &lds[WOFF_US + (hi * 576 + ln31) * 8];
  const unsigned short* Xb1 = Xb0 + BUFU;
  const unsigned short* Ab1 = Ab0 + BUFU;

  STAGE(0);                                  // cc=0 -> buf0
#pragma unroll 1
  for (int t = 0; t < 16; ++t) {
    // ---- phase A: compute buf0 (cc=2t), stage buf1 (cc=2t+1) ----
    STAGE(BUFU);
    asm volatile("s_waitcnt vmcnt(10)" ::: "memory");
    __builtin_amdgcn_s_barrier();
    __builtin_amdgcn_sched_barrier(0);
    __builtin_amdgcn_s_setprio(1);
    COMPUTE(Xb0, Ab0);
    __builtin_amdgcn_s_setprio(0);
    __builtin_amdgcn_sched_barrier(0);
    __builtin_amdgcn_s_barrier();
    // ---- phase B: compute buf1 (cc=2t+1), stage buf0 (cc=2t+2) ----
    if (t < 15) {
      STAGE(0);
      asm volatile("s_waitcnt vmcnt(10)" ::: "memory");
    } else {
      asm volatile("s_waitcnt vmcnt(0)" ::: "memory");
    }
    __builtin_amdgcn_s_barrier();
    __builtin_amdgcn_sched_barrier(0);
    __builtin_amdgcn_s_setprio(1);
    COMPUTE(Xb1, Ab1);
    __builtin_amdgcn_s_setprio(0);
    __builtin_amdgcn_sched_barrier(0);
    __builtin_amdgcn_s_barrier();
  }

  // ---- epilogue: C/D layout col=lane&31, row=(reg&3)+8*(reg>>2)+4*(lane>>5) ----
  int yout = y0 + (wy << 1);
  const float* scp = scale + b * 512 + ob * 64;
  float* op = out + ((size_t)(b * 512 + ob * 64) * 64) * 64;
#pragma unroll
  for (int oh = 0; oh < 2; ++oh) {
#pragma unroll
    for (int rs = 0; rs < 2; ++rs) {
#pragma unroll
      for (int xb = 0; xb < 2; ++xb) {
        const f32x16& A = acc[oh * 4 + rs * 2 + xb];
#pragma unroll
        for (int reg = 0; reg < 16; ++reg) {
          int row = (reg & 3) + 8 * (reg >> 2) + hi * 4;
          int o = oh * 32 + row;
          float sc = scp[o];
          op[((size_t)o * 64 + (yout + rs)) * 64 + xb * 32 + ln31] = A[reg] * sc;
        }
      }
    }
  }
}

extern "C" void kernel_launch(void* const* d_in, const int* in_sizes, int n_in,
                              void* d_out, int out_size, void* d_ws, size_t ws_size,
                              hipStream_t stream) {
  const float* x     = (const float*)d_in[0];  // [8,512,64,64]
  const float* style = (const float*)d_in[1];  // [8,512]
  const float* w     = (const float*)d_in[2];  // [1,512,512,3,3]
  const float* mw    = (const float*)d_in[3];  // [512,512]
  const float* mb    = (const float*)d_in[4];  // [512]
  float* out = (float*)d_out;

  char* ws = (char*)d_ws;
  float* zp    = (float*)ws;                       // 1 KB zeros
  float* s     = (float*)(ws + 1024);              // 16 KB
  float* scale = (float*)(ws + 17408);             // 16 KB
  float* wsq   = (float*)(ws + 33792);             // 1 MB
  unsigned short* wbf = (unsigned short*)(ws + 1082368);   // 4.72 MB  [9][512][512]
  unsigned short* xt  = (unsigned short*)(ws + 5800960);   // 33.5 MB  [8][64][64][512]

  k_mod  <<<16,   256, 0, stream>>>(style, mw, mb, s, zp);
  k_wprep<<<1024, 256, 0, stream>>>(w, wsq, wbf);
  k_scale<<<16,   256, 0, stream>>>(wsq, s, scale);
  k_xt   <<<8192, 256, 0, stream>>>(x, s, xt);
  k_conv <<<512,  256, 0, stream>>>(xt, wbf, scale, zp, out);
}

// Round 4
// 244.590 us; speedup vs baseline: 1.1748x; 1.0177x over previous
//
#include <hip/hip_runtime.h>

// ModulatedConv2d (StyleGAN2): B=8, Cin=Cout=512, k=3, H=W=64.
//   s[b,c]     = style @ (mod_weight/sqrt(512))^T + bias          (fp32)
//   scale[b,o] = cs * rsqrt(cs^2 * sum_c wsq[o,c]*s^2 + eps)
//   out[b,o,p] = scale[b,o] * sum_{c,k} w[o,c,k] * (s[b,c]*x[b,c,p'])
// k_conv v4: LDS-BW-roofline attack. Wave tile 64o x (8y x 32x) -> 16 acc
// frags, 0.33 ds_reads/MFMA (was 0.58). 1 wave/SIMD, 112KB dbuf LDS,
// counted vmcnt(14) pipeline, conflict-free fragment-entry layout.

typedef __bf16 bf16x8 __attribute__((ext_vector_type(8)));
typedef float f32x16 __attribute__((ext_vector_type(16)));

#define AS1 __attribute__((address_space(1)))
#define AS3 __attribute__((address_space(3)))

__device__ __forceinline__ unsigned short f2bf(float f) {
  union { float f; unsigned int u; } v; v.f = f;
  unsigned int u = v.u;
  return (unsigned short)((u + 0x7fffu + ((u >> 16) & 1u)) >> 16);
}

__global__ void k_mod(const float* __restrict__ style, const float* __restrict__ mw,
                      const float* __restrict__ mb, float* __restrict__ s,
                      float* __restrict__ zp) {
  int t = blockIdx.x * 256 + threadIdx.x;   // 4096
  if (blockIdx.x == 0) {                    // 4KB zero page
    zp[threadIdx.x] = 0.f; zp[256 + threadIdx.x] = 0.f;
    zp[512 + threadIdx.x] = 0.f; zp[768 + threadIdx.x] = 0.f;
  }
  int b = t >> 9, c = t & 511;
  float acc = 0.f;
  for (int d = 0; d < 512; ++d) acc += style[b * 512 + d] * mw[c * 512 + d];
  s[t] = acc * 0.04419417382415922f + mb[c];  // 1/sqrt(512)
}

__global__ void k_wprep(const float* __restrict__ w, float* __restrict__ wsq,
                        unsigned short* __restrict__ wbf) {
  int t = blockIdx.x * 256 + threadIdx.x;   // 262144
  int o = t >> 9, c = t & 511;
  const float* wp = w + (size_t)(o * 512 + c) * 9;
  float q = 0.f;
#pragma unroll
  for (int k = 0; k < 9; ++k) {
    float v = wp[k];
    q += v * v;
    wbf[((size_t)k * 512 + o) * 512 + c] = f2bf(v);
  }
  wsq[t] = q;
}

__global__ void k_scale(const float* __restrict__ wsq, const float* __restrict__ s,
                        float* __restrict__ scale) {
  int t = blockIdx.x * 256 + threadIdx.x;   // 4096
  int b = t >> 9, o = t & 511;
  float acc = 0.f;
  for (int c = 0; c < 512; ++c) {
    float sv = s[b * 512 + c];
    acc += wsq[o * 512 + c] * sv * sv;
  }
  const float cs = 0.014731391274719739f;   // 1/sqrt(4608)
  scale[t] = cs * rsqrtf(cs * cs * acc + 1e-8f);
}

// xt[b][y][x][c] = bf16(s[b,c] * x[b,c,y,x])
__global__ void k_xt(const float* __restrict__ x, const float* __restrict__ s,
                     unsigned short* __restrict__ xt) {
  int bid = blockIdx.x;                     // 8192
  int b = bid >> 10, cc = (bid >> 6) & 15, y = bid & 63;
  int t = threadIdx.x;
  int ci = t >> 3, xg = t & 7;
  int c = cc * 32 + ci;
  const float* xp = x + (((size_t)(b * 512 + c) * 64 + y) * 64 + xg * 8);
  float sv = s[b * 512 + c];
  float4 v0 = *(const float4*)xp;
  float4 v1 = *(const float4*)(xp + 4);
  unsigned short r[8];
  r[0] = f2bf(v0.x * sv); r[1] = f2bf(v0.y * sv);
  r[2] = f2bf(v0.z * sv); r[3] = f2bf(v0.w * sv);
  r[4] = f2bf(v1.x * sv); r[5] = f2bf(v1.y * sv);
  r[6] = f2bf(v1.z * sv); r[7] = f2bf(v1.w * sv);
  size_t base = ((size_t)(b * 64 + y) * 64) * 512 + c;
#pragma unroll
  for (int j = 0; j < 8; ++j) xt[base + (size_t)(xg * 8 + j) * 512] = r[j];
}

// ---------------- k_conv v4 ----------------
// Block = 128o x 16y x 32x, 4 waves: (wo in 0..1) x (wyy in 0..1).
// Wave = 64o x (8y x 32x), acc[oh in 0..1][ry in 0..7], 16 f32x16 frags.
// Per 56KB buffer (56 issues x 1024B), entry = 16B = 8 c-values:
//   X: issues 0..19 : e = chunk(0..1)*612 + row(0..17)*34 + xi(0..33)
//      holds xt[yg*16+row-1][xg*32+xi-1][cc*16+chunk*8 ..+7]  (zp if OOB/pad)
//   W: issues 20..55: e2 = chunk*1152 + tap*128 + o(0..127)
//      holds wbf[tap][ob*128+o][cc*16+chunk*8 ..+7]
#define XISS 20
#define NISS 56
#define WOFF_US 10240    // 20 issues * 512 ushorts
#define BUFU    28672    // ushorts per buffer (57344 B)

__global__ __launch_bounds__(256, 1) void k_conv(
    const unsigned short* __restrict__ xt, const unsigned short* __restrict__ wbf,
    const float* __restrict__ scale, const float* __restrict__ zp,
    float* __restrict__ out) {
  __shared__ __align__(16) unsigned short lds[2 * BUFU];  // 114688 B

  int bid = blockIdx.x;            // 256 = 8 b * 4 ob * 4 yg * 2 xg
  int b = bid & 7;                 // XCD k owns batch b=k
  int rest = bid >> 3;
  int ob = rest & 3;
  int rest2 = rest >> 2;
  int yg = rest2 & 3;
  int xg = rest2 >> 2;

  int tid = threadIdx.x;
  int wid = tid >> 6;
  int wo = wid & 1, wyy = wid >> 1;
  int lane = tid & 63, ln31 = lane & 31, hi = lane >> 5;

  // ---- staging source pointers (14 issues per thread), advance 32B/phase ----
  const char* srcp[14];
  const char* xglob = (const char*)(xt + (size_t)b * 64 * 64 * 512);
#pragma unroll
  for (int i = 0; i < 14; ++i) {
    int is = wid + i * 4;
    const char* p;
    if (is < XISS) {
      int e = is * 64 + lane;
      int chunk = e / 612;
      int rem = e - chunk * 612;
      int row = rem / 34;
      int xi = rem - row * 34;
      int y = yg * 16 + row - 1, x = xg * 32 + xi - 1;
      bool ok = (chunk < 2) && (y >= 0) && (y < 64) && (x >= 0) && (x < 64);
      p = ok ? xglob + 2 * ((y * 64 + x) * 512 + chunk * 8) : (const char*)zp;
    } else {
      int e2 = (is - XISS) * 64 + lane;
      int chunk = e2 / 1152;
      int rem = e2 - chunk * 1152;
      int tap = rem >> 7, o = rem & 127;
      p = (const char*)wbf + 2 * ((tap * 512 + ob * 128 + o) * 512 + chunk * 8);
    }
    srcp[i] = p;
  }

  f32x16 acc[16];   // [oh*8 + ry]
#pragma unroll
  for (int i = 0; i < 16; ++i)
    acc[i] = (f32x16){0,0,0,0,0,0,0,0,0,0,0,0,0,0,0,0};

  auto STAGE = [&](int bufu) {
#pragma unroll
    for (int i = 0; i < 14; ++i) {
      __builtin_amdgcn_global_load_lds(
          (const AS1 void*)srcp[i],
          (AS3 void*)&lds[bufu + (wid + i * 4) * 512], 16, 0, 0);
      srcp[i] += 32;
    }
  };

  auto COMPUTE = [&](const unsigned short* Xbp, const unsigned short* Abp) {
#pragma unroll
    for (int kx = 0; kx < 3; ++kx) {
      bf16x8 bv[10];
#pragma unroll
      for (int rr = 0; rr < 10; ++rr)
        bv[rr] = *(const bf16x8*)&Xbp[(rr * 34 + kx) * 8];
#pragma unroll
      for (int ky = 0; ky < 3; ++ky) {
        const int tap = ky * 3 + kx;
        bf16x8 a0 = *(const bf16x8*)&Abp[tap * 1024];
        bf16x8 a1 = *(const bf16x8*)&Abp[tap * 1024 + 256];
#pragma unroll
        for (int ry = 0; ry < 8; ++ry) {
          acc[ry] = __builtin_amdgcn_mfma_f32_32x32x16_bf16(
              a0, bv[ry + ky], acc[ry], 0, 0, 0);
          acc[8 + ry] = __builtin_amdgcn_mfma_f32_32x32x16_bf16(
              a1, bv[ry + ky], acc[8 + ry], 0, 0, 0);
        }
      }
    }
  };

  const unsigned short* Xb0 = &lds[(hi * 612 + wyy * 272 + ln31) * 8];
  const unsigned short* Ab0 = &lds[WOFF_US + (hi * 1152 + wo * 64 + ln31) * 8];
  const unsigned short* Xb1 = Xb0 + BUFU;
  const unsigned short* Ab1 = Ab0 + BUFU;

  STAGE(0);                                  // cc=0 -> buf0
#pragma unroll 1
  for (int t = 0; t < 16; ++t) {
    // phase A: compute buf0 (cc=2t), stage buf1 (cc=2t+1)
    STAGE(BUFU);
    asm volatile("s_waitcnt vmcnt(14)" ::: "memory");
    __builtin_amdgcn_s_barrier();
    __builtin_amdgcn_sched_barrier(0);
    __builtin_amdgcn_s_setprio(1);
    COMPUTE(Xb0, Ab0);
    __builtin_amdgcn_s_setprio(0);
    __builtin_amdgcn_sched_barrier(0);
    __builtin_amdgcn_s_barrier();
    // phase B: compute buf1 (cc=2t+1), stage buf0 (cc=2t+2)
    if (t < 15) {
      STAGE(0);
      asm volatile("s_waitcnt vmcnt(14)" ::: "memory");
    } else {
      asm volatile("s_waitcnt vmcnt(0)" ::: "memory");
    }
    __builtin_amdgcn_s_barrier();
    __builtin_amdgcn_sched_barrier(0);
    __builtin_amdgcn_s_setprio(1);
    COMPUTE(Xb1, Ab1);
    __builtin_amdgcn_s_setprio(0);
    __builtin_amdgcn_sched_barrier(0);
    __builtin_amdgcn_s_barrier();
  }

  // ---- epilogue: C/D layout col=lane&31, row=(reg&3)+8*(reg>>2)+4*(lane>>5) ----
  const float* scp = scale + b * 512 + ob * 128 + wo * 64;
  float* op = out + (((size_t)(b * 512 + ob * 128 + wo * 64) * 64) +
                     yg * 16 + wyy * 8) * 64 + xg * 32 + ln31;
#pragma unroll
  for (int oh = 0; oh < 2; ++oh) {
#pragma unroll
    for (int ry = 0; ry < 8; ++ry) {
      const f32x16& A = acc[oh * 8 + ry];
#pragma unroll
      for (int reg = 0; reg < 16; ++reg) {
        int orow = (reg & 3) + 8 * (reg >> 2) + hi * 4;
        int ol = oh * 32 + orow;
        op[(size_t)ol * 4096 + ry * 64] = A[reg] * scp[ol];
      }
    }
  }
}

extern "C" void kernel_launch(void* const* d_in, const int* in_sizes, int n_in,
                              void* d_out, int out_size, void* d_ws, size_t ws_size,
                              hipStream_t stream) {
  const float* x     = (const float*)d_in[0];  // [8,512,64,64]
  const float* style = (const float*)d_in[1];  // [8,512]
  const float* w     = (const float*)d_in[2];  // [1,512,512,3,3]
  const float* mw    = (const float*)d_in[3];  // [512,512]
  const float* mb    = (const float*)d_in[4];  // [512]
  float* out = (float*)d_out;

  char* ws = (char*)d_ws;
  float* zp    = (float*)ws;                       // 4 KB zeros
  float* s     = (float*)(ws + 4096);              // 16 KB
  float* scale = (float*)(ws + 20480);             // 16 KB
  float* wsq   = (float*)(ws + 36864);             // 1 MB
  unsigned short* wbf = (unsigned short*)(ws + 1085440);   // 4.72 MB [9][512][512]
  unsigned short* xt  = (unsigned short*)(ws + 5804032);   // 33.5 MB [8][64][64][512]

  k_mod  <<<16,   256, 0, stream>>>(style, mw, mb, s, zp);
  k_wprep<<<1024, 256, 0, stream>>>(w, wsq, wbf);
  k_scale<<<16,   256, 0, stream>>>(wsq, s, scale);
  k_xt   <<<8192, 256, 0, stream>>>(x, s, xt);
  k_conv <<<256,  256, 0, stream>>>(xt, wbf, scale, zp, out);
}

// Round 5
// 220.383 us; speedup vs baseline: 1.3038x; 1.1098x over previous
//
#include <hip/hip_runtime.h>

// ModulatedConv2d (StyleGAN2): B=8, Cin=Cout=512, k=3, H=W=64.
//   s[b,c]     = style @ (mod_weight/sqrt(512))^T + bias          (fp32)
//   scale[b,o] = cs * rsqrt(cs^2 * sum_c wsq[o,c]*s^2 + eps)
//   out[b,o,p] = scale[b,o] * sum_{c,k} w[o,c,k] * (s[b,c]*x[b,c,p'])
// k_conv v5: latency-hiding attack. Same 128o x 16y x 32x block tile and
// 2x56KB dbuf LDS as v4, but 8 waves (512 thr) = 2 waves/SIMD, wave tile
// 64o x 4y x 32x (8 acc frags, ~190 VGPR). Single barrier per phase:
// STAGE(next) -> compute(cur) -> vmcnt(0)+lgkmcnt(0) -> s_barrier.

typedef __bf16 bf16x8 __attribute__((ext_vector_type(8)));
typedef float f32x16 __attribute__((ext_vector_type(16)));

#define AS1 __attribute__((address_space(1)))
#define AS3 __attribute__((address_space(3)))

__device__ __forceinline__ unsigned short f2bf(float f) {
  union { float f; unsigned int u; } v; v.f = f;
  unsigned int u = v.u;
  return (unsigned short)((u + 0x7fffu + ((u >> 16) & 1u)) >> 16);
}

__global__ void k_mod(const float* __restrict__ style, const float* __restrict__ mw,
                      const float* __restrict__ mb, float* __restrict__ s,
                      float* __restrict__ zp) {
  int t = blockIdx.x * 256 + threadIdx.x;   // 4096
  if (blockIdx.x == 0) {                    // 4KB zero page
    zp[threadIdx.x] = 0.f; zp[256 + threadIdx.x] = 0.f;
    zp[512 + threadIdx.x] = 0.f; zp[768 + threadIdx.x] = 0.f;
  }
  int b = t >> 9, c = t & 511;
  float acc = 0.f;
  for (int d = 0; d < 512; ++d) acc += style[b * 512 + d] * mw[c * 512 + d];
  s[t] = acc * 0.04419417382415922f + mb[c];  // 1/sqrt(512)
}

__global__ void k_wprep(const float* __restrict__ w, float* __restrict__ wsq,
                        unsigned short* __restrict__ wbf) {
  int t = blockIdx.x * 256 + threadIdx.x;   // 262144
  int o = t >> 9, c = t & 511;
  const float* wp = w + (size_t)(o * 512 + c) * 9;
  float q = 0.f;
#pragma unroll
  for (int k = 0; k < 9; ++k) {
    float v = wp[k];
    q += v * v;
    wbf[((size_t)k * 512 + o) * 512 + c] = f2bf(v);
  }
  wsq[t] = q;
}

__global__ void k_scale(const float* __restrict__ wsq, const float* __restrict__ s,
                        float* __restrict__ scale) {
  int t = blockIdx.x * 256 + threadIdx.x;   // 4096
  int b = t >> 9, o = t & 511;
  float acc = 0.f;
  for (int c = 0; c < 512; ++c) {
    float sv = s[b * 512 + c];
    acc += wsq[o * 512 + c] * sv * sv;
  }
  const float cs = 0.014731391274719739f;   // 1/sqrt(4608)
  scale[t] = cs * rsqrtf(cs * cs * acc + 1e-8f);
}

// xt[b][y][x][c] = bf16(s[b,c] * x[b,c,y,x])
__global__ void k_xt(const float* __restrict__ x, const float* __restrict__ s,
                     unsigned short* __restrict__ xt) {
  int bid = blockIdx.x;                     // 8192
  int b = bid >> 10, cc = (bid >> 6) & 15, y = bid & 63;
  int t = threadIdx.x;
  int ci = t >> 3, xg = t & 7;
  int c = cc * 32 + ci;
  const float* xp = x + (((size_t)(b * 512 + c) * 64 + y) * 64 + xg * 8);
  float sv = s[b * 512 + c];
  float4 v0 = *(const float4*)xp;
  float4 v1 = *(const float4*)(xp + 4);
  unsigned short r[8];
  r[0] = f2bf(v0.x * sv); r[1] = f2bf(v0.y * sv);
  r[2] = f2bf(v0.z * sv); r[3] = f2bf(v0.w * sv);
  r[4] = f2bf(v1.x * sv); r[5] = f2bf(v1.y * sv);
  r[6] = f2bf(v1.z * sv); r[7] = f2bf(v1.w * sv);
  size_t base = ((size_t)(b * 64 + y) * 64) * 512 + c;
#pragma unroll
  for (int j = 0; j < 8; ++j) xt[base + (size_t)(xg * 8 + j) * 512] = r[j];
}

// ---------------- k_conv v5 ----------------
// Block = 128o x 16y x 32x, 8 waves: wid = wyy(0..3)*2 + wo(0..1).
// Wave = 64o x (4y x 32x), acc[oh in 0..1][ry in 0..3], 8 f32x16 frags.
// Per 56KB buffer (56 issues x 1024B), entry = 16B = 8 c-values:
//   X: issues 0..19 : e = chunk(0..1)*612 + row(0..17)*34 + xi(0..33)
//      holds xt[yg*16+row-1][xg*32+xi-1][cc*16+chunk*8 ..+7]  (zp if OOB/pad)
//   W: issues 20..55: e2 = chunk*1152 + tap*128 + o(0..127)
//      holds wbf[tap][ob*128+o][cc*16+chunk*8 ..+7]
#define XISS 20
#define WOFF_US 10240    // 20 issues * 512 ushorts
#define BUFU    28672    // ushorts per buffer (57344 B)

__global__ __launch_bounds__(512, 2) void k_conv(
    const unsigned short* __restrict__ xt, const unsigned short* __restrict__ wbf,
    const float* __restrict__ scale, const float* __restrict__ zp,
    float* __restrict__ out) {
  __shared__ __align__(16) unsigned short lds[2 * BUFU];  // 114688 B

  int bid = blockIdx.x;            // 256 = 8 b * 4 ob * 4 yg * 2 xg
  int b = bid & 7;                 // XCD k owns batch b=k
  int rest = bid >> 3;
  int ob = rest & 3;
  int rest2 = rest >> 2;
  int yg = rest2 & 3;
  int xg = rest2 >> 2;

  int tid = threadIdx.x;
  int wid = tid >> 6;              // 0..7
  int wo = wid & 1, wyy = wid >> 1;
  int lane = tid & 63, ln31 = lane & 31, hi = lane >> 5;

  // ---- staging source pointers (7 issues per thread), advance 32B/phase ----
  const char* srcp[7];
  const char* xglob = (const char*)(xt + (size_t)b * 64 * 64 * 512);
#pragma unroll
  for (int i = 0; i < 7; ++i) {
    int is = wid + i * 8;          // 0..55
    const char* p;
    if (is < XISS) {
      int e = is * 64 + lane;
      int chunk = e / 612;
      int rem = e - chunk * 612;
      int row = rem / 34;
      int xi = rem - row * 34;
      int y = yg * 16 + row - 1, x = xg * 32 + xi - 1;
      bool ok = (chunk < 2) && (y >= 0) && (y < 64) && (x >= 0) && (x < 64);
      p = ok ? xglob + 2 * ((y * 64 + x) * 512 + chunk * 8) : (const char*)zp;
    } else {
      int e2 = (is - XISS) * 64 + lane;
      int chunk = e2 / 1152;
      int rem = e2 - chunk * 1152;
      int tap = rem >> 7, o = rem & 127;
      p = (const char*)wbf + 2 * ((tap * 512 + ob * 128 + o) * 512 + chunk * 8);
    }
    srcp[i] = p;
  }

  f32x16 acc[8];   // [oh*4 + ry]
#pragma unroll
  for (int i = 0; i < 8; ++i)
    acc[i] = (f32x16){0,0,0,0,0,0,0,0,0,0,0,0,0,0,0,0};

  auto STAGE = [&](int bufu) {
#pragma unroll
    for (int i = 0; i < 7; ++i) {
      __builtin_amdgcn_global_load_lds(
          (const AS1 void*)srcp[i],
          (AS3 void*)&lds[bufu + (wid + i * 8) * 512], 16, 0, 0);
      srcp[i] += 32;
    }
  };

  auto COMPUTE = [&](const unsigned short* Xbp, const unsigned short* Abp) {
#pragma unroll
    for (int kx = 0; kx < 3; ++kx) {
      bf16x8 bv[6];   // rows wyy*4 + 0..5 at this kx
#pragma unroll
      for (int rr = 0; rr < 6; ++rr)
        bv[rr] = *(const bf16x8*)&Xbp[(rr * 34 + kx) * 8];
#pragma unroll
      for (int ky = 0; ky < 3; ++ky) {
        const int tap = ky * 3 + kx;
        bf16x8 a0 = *(const bf16x8*)&Abp[tap * 1024];
        bf16x8 a1 = *(const bf16x8*)&Abp[tap * 1024 + 256];
#pragma unroll
        for (int ry = 0; ry < 4; ++ry) {
          acc[ry] = __builtin_amdgcn_mfma_f32_32x32x16_bf16(
              a0, bv[ry + ky], acc[ry], 0, 0, 0);
          acc[4 + ry] = __builtin_amdgcn_mfma_f32_32x32x16_bf16(
              a1, bv[ry + ky], acc[4 + ry], 0, 0, 0);
        }
      }
    }
  };

  const unsigned short* Xb0 = &lds[(hi * 612 + wyy * 4 * 34 + ln31) * 8];
  const unsigned short* Ab0 = &lds[WOFF_US + (hi * 1152 + wo * 64 + ln31) * 8];
  const unsigned short* Xb1 = Xb0 + BUFU;
  const unsigned short* Ab1 = Ab0 + BUFU;

  STAGE(0);                                  // cc=0 -> buf0
  asm volatile("s_waitcnt vmcnt(0) lgkmcnt(0)" ::: "memory");
  __builtin_amdgcn_s_barrier();
  __builtin_amdgcn_sched_barrier(0);

#pragma unroll 1
  for (int t = 0; t < 16; ++t) {
    // phase A: stage buf1 (cc=2t+1), compute buf0 (cc=2t)
    STAGE(BUFU);
    __builtin_amdgcn_s_setprio(1);
    COMPUTE(Xb0, Ab0);
    __builtin_amdgcn_s_setprio(0);
    asm volatile("s_waitcnt vmcnt(0) lgkmcnt(0)" ::: "memory");
    __builtin_amdgcn_s_barrier();
    __builtin_amdgcn_sched_barrier(0);
    // phase B: stage buf0 (cc=2t+2), compute buf1 (cc=2t+1)
    if (t < 15) STAGE(0);
    __builtin_amdgcn_s_setprio(1);
    COMPUTE(Xb1, Ab1);
    __builtin_amdgcn_s_setprio(0);
    asm volatile("s_waitcnt vmcnt(0) lgkmcnt(0)" ::: "memory");
    __builtin_amdgcn_s_barrier();
    __builtin_amdgcn_sched_barrier(0);
  }

  // ---- epilogue: C/D layout col=lane&31, row=(reg&3)+8*(reg>>2)+4*(lane>>5) ----
  const float* scp = scale + b * 512 + ob * 128 + wo * 64;
  float* op = out + (((size_t)(b * 512 + ob * 128 + wo * 64) * 64) +
                     yg * 16 + wyy * 4) * 64 + xg * 32 + ln31;
#pragma unroll
  for (int oh = 0; oh < 2; ++oh) {
#pragma unroll
    for (int ry = 0; ry < 4; ++ry) {
      const f32x16& A = acc[oh * 4 + ry];
#pragma unroll
      for (int reg = 0; reg < 16; ++reg) {
        int orow = (reg & 3) + 8 * (reg >> 2) + hi * 4;
        int ol = oh * 32 + orow;
        op[(size_t)ol * 4096 + ry * 64] = A[reg] * scp[ol];
      }
    }
  }
}

extern "C" void kernel_launch(void* const* d_in, const int* in_sizes, int n_in,
                              void* d_out, int out_size, void* d_ws, size_t ws_size,
                              hipStream_t stream) {
  const float* x     = (const float*)d_in[0];  // [8,512,64,64]
  const float* style = (const float*)d_in[1];  // [8,512]
  const float* w     = (const float*)d_in[2];  // [1,512,512,3,3]
  const float* mw    = (const float*)d_in[3];  // [512,512]
  const float* mb    = (const float*)d_in[4];  // [512]
  float* out = (float*)d_out;

  char* ws = (char*)d_ws;
  float* zp    = (float*)ws;                       // 4 KB zeros
  float* s     = (float*)(ws + 4096);              // 16 KB
  float* scale = (float*)(ws + 20480);             // 16 KB
  float* wsq   = (float*)(ws + 36864);             // 1 MB
  unsigned short* wbf = (unsigned short*)(ws + 1085440);   // 4.72 MB [9][512][512]
  unsigned short* xt  = (unsigned short*)(ws + 5804032);   // 33.5 MB [8][64][64][512]

  k_mod  <<<16,   256, 0, stream>>>(style, mw, mb, s, zp);
  k_wprep<<<1024, 256, 0, stream>>>(w, wsq, wbf);
  k_scale<<<16,   256, 0, stream>>>(wsq, s, scale);
  k_xt   <<<8192, 256, 0, stream>>>(x, s, xt);
  k_conv <<<256,  512, 0, stream>>>(xt, wbf, scale, zp, out);
}